// Round 7
// baseline (648.534 us; speedup 1.0000x reference)
//
#include <hip/hip_runtime.h>
#include <hip/hip_bf16.h>
#include <math.h>

#define B_ 4
#define S_ 2048
#define H_ 512
#define HEADS_ 8
#define DK_ 64
#define NROWS_ (B_*S_)          // 8192
#define LN_EPS_ 1e-5f
#define NEG_INF_ -1e30f
// Q pre-scale: 1/sqrt(DK) * log2(e)  (softmax done in exp2 domain)
#define QSCALE_ (0.125f * 1.44269504088896f)

typedef short s8v __attribute__((ext_vector_type(8)));   // 8 bf16 (4 VGPRs)
typedef short s4v __attribute__((ext_vector_type(4)));   // 4 bf16 (2 VGPRs)
typedef float f4v __attribute__((ext_vector_type(4)));

__device__ __forceinline__ unsigned short f2bf(float f) {
    unsigned int u = __float_as_uint(f);
    u += 0x7FFFu + ((u >> 16) & 1u);     // round-to-nearest-even
    return (unsigned short)(u >> 16);
}

__device__ __forceinline__ s4v pk4bf(float a, float b, float c, float d) {
    union { __hip_bfloat162 h[2]; s4v v; } u;
    u.h[0] = __float22bfloat162_rn(float2{a, b});
    u.h[1] = __float22bfloat162_rn(float2{c, d});
    return u.v;
}

// ---------------------------------------------------------------------------
// Kernel 0: weight transpose -> Wt (2048 x 512 bf16).
//   rows 0..511: Wq (scaled QSCALE_) | 512..1023: Wk | 1024..1535: Wv | 1536..: Wo
// ---------------------------------------------------------------------------
__global__ __launch_bounds__(256) void wt_kernel(
        const float* __restrict__ Wq, const float* __restrict__ Wk,
        const float* __restrict__ Wv, const float* __restrict__ Wo,
        unsigned short* __restrict__ Wt) {
    __shared__ float tile[32][33];
    int z = blockIdx.z;
    int k0 = blockIdx.y * 32, c0 = blockIdx.x * 32;
    const float* src;
    int ld, drow;
    float scale = 1.f;
    if (z < 24) {
        if (blockIdx.x >= 2) return;
        int zw = z >> 3, head = z & 7;
        const float* W = (zw == 0) ? Wq : (zw == 1) ? Wk : Wv;
        if (zw == 0) scale = QSCALE_;
        src = W + (size_t)head * H_ * DK_;
        ld = DK_;
        drow = zw * 512 + head * 64;
    } else {
        src = Wo; ld = H_; drow = 1536;
    }
    int tx = threadIdx.x & 31, ty = threadIdx.x >> 5;
    #pragma unroll
    for (int i = 0; i < 4; i++)
        tile[ty * 4 + i][tx] = src[(size_t)(k0 + ty * 4 + i) * ld + c0 + tx];
    __syncthreads();
    #pragma unroll
    for (int i = 0; i < 4; i++) {
        int cc = ty * 4 + i;
        Wt[(size_t)(drow + c0 + cc) * 512 + k0 + tx] = f2bf(tile[tx][cc] * scale);
    }
}

// ---------------------------------------------------------------------------
// Kernel 1: LayerNorm, wave-per-row, float4 loads. grid NROWS/4, block 256.
// ---------------------------------------------------------------------------
__global__ __launch_bounds__(256) void ln_kernel(
        const float* __restrict__ x, const float* __restrict__ gamma,
        const float* __restrict__ beta, float* __restrict__ xn,
        unsigned short* __restrict__ xnb) {
    int row  = blockIdx.x * 4 + (threadIdx.x >> 6);
    int lane = threadIdx.x & 63;
    const float4* xr = (const float4*)(x + (size_t)row * H_ + lane * 8);
    float4 a = xr[0], d = xr[1];
    float s  = (a.x + a.y) + (a.z + a.w) + (d.x + d.y) + (d.z + d.w);
    float ss = (a.x*a.x + a.y*a.y) + (a.z*a.z + a.w*a.w)
             + (d.x*d.x + d.y*d.y) + (d.z*d.z + d.w*d.w);
    #pragma unroll
    for (int i = 1; i < 64; i <<= 1) {
        s  += __shfl_xor(s, i, 64);
        ss += __shfl_xor(ss, i, 64);
    }
    float mu  = s * (1.f / 512.f);
    float var = ss * (1.f / 512.f) - mu * mu;
    float rstd = rsqrtf(var + LN_EPS_);
    const float4* gp = (const float4*)(gamma + lane * 8);
    const float4* bp = (const float4*)(beta + lane * 8);
    float4 g0 = gp[0], g1 = gp[1], b0 = bp[0], b1 = bp[1];
    float4 y0, y1;
    y0.x = (a.x - mu) * rstd * g0.x + b0.x;
    y0.y = (a.y - mu) * rstd * g0.y + b0.y;
    y0.z = (a.z - mu) * rstd * g0.z + b0.z;
    y0.w = (a.w - mu) * rstd * g0.w + b0.w;
    y1.x = (d.x - mu) * rstd * g1.x + b1.x;
    y1.y = (d.y - mu) * rstd * g1.y + b1.y;
    y1.z = (d.z - mu) * rstd * g1.z + b1.z;
    y1.w = (d.w - mu) * rstd * g1.w + b1.w;
    float4* xo = (float4*)(xn + (size_t)row * H_ + lane * 8);
    xo[0] = y0; xo[1] = y1;
    union { s4v h[2]; s8v v; } pk;
    pk.h[0] = pk4bf(y0.x, y0.y, y0.z, y0.w);
    pk.h[1] = pk4bf(y1.x, y1.y, y1.z, y1.w);
    *(s8v*)(xnb + (size_t)row * H_ + lane * 8) = pk.v;
}

// ---------------------------------------------------------------------------
// Shared MFMA GEMM tile loop (symmetric in A/B; unchanged).
// ---------------------------------------------------------------------------
#define BK_ 32
__device__ __forceinline__ void gemm_tile(
        const unsigned short* __restrict__ A,
        const unsigned short* __restrict__ Bt,
        int r0, int j0, f4v acc[4][4]) {
    __shared__ unsigned short As[128][BK_ + 8];
    __shared__ unsigned short Bs[128][BK_ + 8];
    int t = threadIdx.x;
    int wv = t >> 6, L = t & 63, c = L & 15, g = L >> 4;
    int m_base = (wv & 1) * 64, n_base = (wv >> 1) * 64;
    #pragma unroll
    for (int i = 0; i < 4; i++)
        #pragma unroll
        for (int j = 0; j < 4; j++) acc[i][j] = (f4v){0.f, 0.f, 0.f, 0.f};
    for (int k0 = 0; k0 < 512; k0 += BK_) {
        __syncthreads();
        #pragma unroll
        for (int i = 0; i < 2; i++) {
            int idx = t + i * 256;
            int m = idx >> 2, k8 = idx & 3;
            s8v va = *(const s8v*)(A  + (size_t)(r0 + m) * 512 + k0 + k8 * 8);
            s8v vb = *(const s8v*)(Bt + (size_t)(j0 + m) * 512 + k0 + k8 * 8);
            *(s8v*)(&As[m][k8 * 8]) = va;
            *(s8v*)(&Bs[m][k8 * 8]) = vb;
        }
        __syncthreads();
        s8v a[4], b[4];
        #pragma unroll
        for (int i = 0; i < 4; i++)
            a[i] = *(const s8v*)(&As[m_base + i * 16 + c][g * 8]);
        #pragma unroll
        for (int j = 0; j < 4; j++)
            b[j] = *(const s8v*)(&Bs[n_base + j * 16 + c][g * 8]);
        #pragma unroll
        for (int i = 0; i < 4; i++)
            #pragma unroll
            for (int j = 0; j < 4; j++)
                acc[i][j] = __builtin_amdgcn_mfma_f32_16x16x32_bf16(
                    a[i], b[j], acc[i][j], 0, 0, 0);
    }
}

// ---------------------------------------------------------------------------
// Kernel 2: QKV GEMM (unchanged from round 6).
// ---------------------------------------------------------------------------
__global__ __launch_bounds__(256) void qkv_gemm(
        const unsigned short* __restrict__ xnb,
        const unsigned short* __restrict__ Wt,
        unsigned short* __restrict__ Qb, unsigned short* __restrict__ Kf,
        unsigned short* __restrict__ Vf) {
    f4v acc[4][4];
    int t = threadIdx.x;
    int wv = t >> 6, L = t & 63, c = L & 15, g = L >> 4;
    int rb = wv & 1, cb = wv >> 1;
    if (blockIdx.x < 8) {
        int m0 = blockIdx.x * 128, n0 = blockIdx.y * 128;
        gemm_tile(Wt, xnb, m0, n0, acc);
        int R0 = m0 + rb * 64;            // Wt-row base (64-aligned, one head)
        int C0 = n0 + cb * 64;            // token base (64-aligned)
        int hd = (R0 >> 6) & 7;
        int b  = C0 >> 11, srow0 = C0 & 2047;
        size_t bhbase = (size_t)(b * HEADS_ + hd) * S_ * DK_;
        if (R0 < 512) {                   // ---- Q: row-major (token, dk)
            #pragma unroll
            for (int msub = 0; msub < 4; msub++) {
                int dk4 = msub * 16 + g * 4;
                #pragma unroll
                for (int nsub = 0; nsub < 4; nsub++) {
                    int tok = srow0 + nsub * 16 + c;
                    s4v v = pk4bf(acc[msub][nsub][0], acc[msub][nsub][1],
                                  acc[msub][nsub][2], acc[msub][nsub][3]);
                    *(s4v*)(Qb + bhbase + (size_t)tok * DK_ + dk4) = v;
                }
            }
        } else {                          // ---- K: fragment-major
            unsigned short* dst = Kf + bhbase + (size_t)(srow0 >> 6) * 4096;
            #pragma unroll
            for (int msub = 0; msub < 4; msub++) {
                int gx = (msub & 1) * 2 + (g >> 1);
                int slotbase = (g & 1) * 4 + (msub >> 1) * 8;
                #pragma unroll
                for (int nsub = 0; nsub < 4; nsub++) {
                    s4v v = pk4bf(acc[msub][nsub][0], acc[msub][nsub][1],
                                  acc[msub][nsub][2], acc[msub][nsub][3]);
                    *(s4v*)(dst + nsub * 1024 + (gx * 16 + c) * 16 + slotbase) = v;
                }
            }
        }
    } else {
        int r0 = blockIdx.y * 128, j0 = 1024 + (blockIdx.x - 8) * 128;
        gemm_tile(xnb, Wt, r0, j0, acc);
        int R0 = r0 + rb * 64;            // token base
        int C0 = j0 + cb * 64;            // col base
        int hd = (C0 >> 6) & 7;
        int b = R0 >> 11, srow0 = R0 & 2047;
        unsigned short* dst = Vf + (size_t)(b * HEADS_ + hd) * S_ * DK_
                              + (size_t)(srow0 >> 6) * 4096;
        #pragma unroll
        for (int msub = 0; msub < 4; msub++)
            #pragma unroll
            for (int nsub = 0; nsub < 4; nsub++) {
                s4v v = pk4bf(acc[msub][nsub][0], acc[msub][nsub][1],
                              acc[msub][nsub][2], acc[msub][nsub][3]);
                *(s4v*)(dst + nsub * 1024 + (g * 16 + c) * 16 + msub * 4) = v;
            }
    }
}

// ---------------------------------------------------------------------------
// Kernel 3: flash attention, key-split within block for occupancy.
// Block = 512 threads = 8 waves: wave wv = qsub (wv&3) x keypart (wv>>2).
// Each wave: 16 q-rows x 1024 keys (16 iters). No online max (raw exp2
// accumulation is order-independent), so keyparts combine by a single LDS
// add at the end. 1024 blocks x 512 thr = 32 waves/CU = occupancy cap.
// ---------------------------------------------------------------------------
__global__ __launch_bounds__(512, 8) void attn_kernel(
        const unsigned short* __restrict__ Qb,
        const unsigned short* __restrict__ Kf,
        const unsigned short* __restrict__ Vf,
        const int* __restrict__ mask,
        unsigned short* __restrict__ hb) {
    __shared__ float red[4][64][17];     // [qsub][lane][16 acc + l]

    int wv   = threadIdx.x >> 6;
    int qsub = wv & 3;
    int kp   = wv >> 2;                  // keypart: 0 or 1
    int L  = threadIdx.x & 63;
    int c  = L & 15;            // q within wave-tile
    int g  = L >> 4;            // quad
    int bh = blockIdx.y;
    int b  = bh >> 3, n = bh & 7;
    int q0 = blockIdx.x * 64 + qsub * 16;

    const unsigned short* Qbase = Qb + (size_t)bh * S_ * DK_;
    const unsigned short* Kp = Kf + (size_t)bh * S_ * DK_ + (size_t)kp * 16 * 4096 + L * 16;
    const unsigned short* Vp = Vf + (size_t)bh * S_ * DK_ + (size_t)kp * 16 * 4096 + L * 16;
    const int* mrow = mask + b * S_ + kp * 1024;

    s8v qf0 = *(const s8v*)(Qbase + (size_t)(q0 + c) * DK_ + g * 8);
    s8v qf1 = *(const s8v*)(Qbase + (size_t)(q0 + c) * DK_ + 32 + g * 8);

    f4v acc[4];                 // O^T: d = dsub*16 + g*4 + r, q = q0 + c
    #pragma unroll
    for (int i = 0; i < 4; i++) acc[i] = (f4v){0.f, 0.f, 0.f, 0.f};
    float lac[4] = {0.f, 0.f, 0.f, 0.f};

    // prefetch K + mask for kb = 0
    s8v ka[4], kb2[4];
    int4 mk[4];
    #pragma unroll
    for (int ks = 0; ks < 4; ks++) {
        ka[ks]  = *(const s8v*)(Kp + ks * 1024);
        kb2[ks] = *(const s8v*)(Kp + ks * 1024 + 8);
        mk[ks]  = *(const int4*)(mrow + ks * 16 + g * 4);
    }

    for (int kb = 0; kb < 16; kb++) {
        // ---- V loads for current block (consumed after softmax) ----
        const unsigned short* Vn = Vp + (size_t)kb * 4096;
        s8v va[4], vb[4];
        #pragma unroll
        for (int ds = 0; ds < 4; ds++) {
            va[ds] = *(const s8v*)(Vn + ds * 1024);
            vb[ds] = *(const s8v*)(Vn + ds * 1024 + 8);
        }
        // ---- S^T MFMAs (keys on regs g*4+r, q on lanes c) ----
        f4v s[4];
        #pragma unroll
        for (int ks = 0; ks < 4; ks++) {
            f4v sv = (f4v){0.f, 0.f, 0.f, 0.f};
            sv = __builtin_amdgcn_mfma_f32_16x16x32_bf16(ka[ks],  qf0, sv, 0, 0, 0);
            sv = __builtin_amdgcn_mfma_f32_16x16x32_bf16(kb2[ks], qf1, sv, 0, 0, 0);
            s[ks] = sv;
        }
        // ---- K + mask prefetch for next block ----
        int4 mcur[4];
        #pragma unroll
        for (int ks = 0; ks < 4; ks++) mcur[ks] = mk[ks];
        if (kb < 15) {
            const unsigned short* Kn = Kp + (size_t)(kb + 1) * 4096;
            #pragma unroll
            for (int ks = 0; ks < 4; ks++) {
                ka[ks]  = *(const s8v*)(Kn + ks * 1024);
                kb2[ks] = *(const s8v*)(Kn + ks * 1024 + 8);
                mk[ks]  = *(const int4*)(mrow + (kb + 1) * 64 + ks * 16 + g * 4);
            }
        }
        // ---- mask + exp2 + partial sums (no max, no rescale) ----
        float p[4][4];
        #pragma unroll
        for (int ks = 0; ks < 4; ks++) {
            p[ks][0] = __builtin_amdgcn_exp2f(mcur[ks].x ? s[ks][0] : NEG_INF_);
            p[ks][1] = __builtin_amdgcn_exp2f(mcur[ks].y ? s[ks][1] : NEG_INF_);
            p[ks][2] = __builtin_amdgcn_exp2f(mcur[ks].z ? s[ks][2] : NEG_INF_);
            p[ks][3] = __builtin_amdgcn_exp2f(mcur[ks].w ? s[ks][3] : NEG_INF_);
            #pragma unroll
            for (int r = 0; r < 4; r++) lac[r] += p[ks][r];
        }
        // ---- P fragments (regs already B-frag of 16x16x16) ----
        s4v pf[4];
        #pragma unroll
        for (int ks = 0; ks < 4; ks++)
            pf[ks] = pk4bf(p[ks][0], p[ks][1], p[ks][2], p[ks][3]);
        // ---- O^T += V^T . P^T ----
        #pragma unroll
        for (int dsub = 0; dsub < 4; dsub++) {
            s4v v0 = __builtin_shufflevector(va[dsub], va[dsub], 0, 1, 2, 3);
            s4v v1 = __builtin_shufflevector(va[dsub], va[dsub], 4, 5, 6, 7);
            s4v v2 = __builtin_shufflevector(vb[dsub], vb[dsub], 0, 1, 2, 3);
            s4v v3 = __builtin_shufflevector(vb[dsub], vb[dsub], 4, 5, 6, 7);
            acc[dsub] = __builtin_amdgcn_mfma_f32_16x16x16bf16_1k(v0, pf[0], acc[dsub], 0, 0, 0);
            acc[dsub] = __builtin_amdgcn_mfma_f32_16x16x16bf16_1k(v1, pf[1], acc[dsub], 0, 0, 0);
            acc[dsub] = __builtin_amdgcn_mfma_f32_16x16x16bf16_1k(v2, pf[2], acc[dsub], 0, 0, 0);
            acc[dsub] = __builtin_amdgcn_mfma_f32_16x16x16bf16_1k(v3, pf[3], acc[dsub], 0, 0, 0);
        }
    }

    float l = (lac[0] + lac[1]) + (lac[2] + lac[3]);
    l += __shfl_xor(l, 16, 64);
    l += __shfl_xor(l, 32, 64);

    // ---- combine keyparts through LDS ----
    if (kp == 1) {
        float* dst = &red[qsub][L][0];
        #pragma unroll
        for (int d = 0; d < 4; d++) {
            dst[d * 4 + 0] = acc[d][0]; dst[d * 4 + 1] = acc[d][1];
            dst[d * 4 + 2] = acc[d][2]; dst[d * 4 + 3] = acc[d][3];
        }
        dst[16] = l;
    }
    __syncthreads();
    if (kp == 0) {
        const float* src = &red[qsub][L][0];
        float inv = 1.f / (l + src[16]);
        unsigned short* hp = hb + (size_t)(b * S_ + q0 + c) * H_ + n * DK_ + g * 4;
        #pragma unroll
        for (int dsub = 0; dsub < 4; dsub++) {
            s4v o4 = pk4bf((acc[dsub][0] + src[dsub * 4 + 0]) * inv,
                           (acc[dsub][1] + src[dsub * 4 + 1]) * inv,
                           (acc[dsub][2] + src[dsub * 4 + 2]) * inv,
                           (acc[dsub][3] + src[dsub * 4 + 3]) * inv);
            *(s4v*)(hp + dsub * 16) = o4;
        }
    }
}

// ---------------------------------------------------------------------------
// Kernel 4: out = (hb @ Wot^T + xn) * mask. grid (4, 64).
// ---------------------------------------------------------------------------
__global__ __launch_bounds__(256) void out_gemm(
        const unsigned short* __restrict__ hb,
        const unsigned short* __restrict__ Wot,
        const float* __restrict__ xn, const int* __restrict__ mask,
        float* __restrict__ out) {
    f4v acc[4][4];
    int r0 = blockIdx.y * 128, j0 = blockIdx.x * 128;
    gemm_tile(hb, Wot, r0, j0, acc);
    int t = threadIdx.x;
    int wv = t >> 6, L = t & 63, c = L & 15, g = L >> 4;
    int mrow = r0 + (wv & 1) * 64 + g * 4;
    int ncol = j0 + (wv >> 1) * 64 + c;
    #pragma unroll
    for (int msub = 0; msub < 4; msub++) {
        #pragma unroll
        for (int rr = 0; rr < 4; rr++) {
            int row = mrow + msub * 16 + rr;
            float mf = (float)mask[row];
            #pragma unroll
            for (int nsub = 0; nsub < 4; nsub++) {
                int col = ncol + nsub * 16;
                size_t o = (size_t)row * H_ + col;
                out[o] = (acc[msub][nsub][rr] + xn[o]) * mf;
            }
        }
    }
}

// ---------------------------------------------------------------------------
extern "C" void kernel_launch(void* const* d_in, const int* in_sizes, int n_in,
                              void* d_out, int out_size, void* d_ws, size_t ws_size,
                              hipStream_t stream) {
    const float* x     = (const float*)d_in[0];
    const int*   mask  = (const int*)d_in[1];
    const float* Wq    = (const float*)d_in[2];
    const float* Wk    = (const float*)d_in[3];
    const float* Wv    = (const float*)d_in[4];
    const float* Wo    = (const float*)d_in[5];
    const float* gamma = (const float*)d_in[6];
    const float* beta  = (const float*)d_in[7];
    float* out = (float*)d_out;

    size_t nelem = (size_t)NROWS_ * H_;   // 4M elements
    char* ws = (char*)d_ws;
    float*          xn  = (float*)ws;          ws += nelem * 4;   // 16 MB
    unsigned short* xnb = (unsigned short*)ws; ws += nelem * 2;   // 8 MB
    unsigned short* hb  = (unsigned short*)ws; ws += nelem * 2;   // 8 MB
    unsigned short* Qb  = (unsigned short*)ws; ws += nelem * 2;   // 8 MB
    unsigned short* Kf  = (unsigned short*)ws; ws += nelem * 2;   // 8 MB
    unsigned short* Vf  = (unsigned short*)ws; ws += nelem * 2;   // 8 MB
    unsigned short* Wt  = (unsigned short*)ws;                    // 2 MB

    wt_kernel<<<dim3(16, 16, 25), 256, 0, stream>>>(Wq, Wk, Wv, Wo, Wt);
    ln_kernel<<<NROWS_ / 4, 256, 0, stream>>>(x, gamma, beta, xn, xnb);
    qkv_gemm<<<dim3(12, 64), 256, 0, stream>>>(xnb, Wt, Qb, Kf, Vf);
    attn_kernel<<<dim3(S_ / 64, B_ * HEADS_), 512, 0, stream>>>(
        Qb, Kf, Vf, mask, hb);
    out_gemm<<<dim3(4, 64), 256, 0, stream>>>(
        hb, Wt + (size_t)1536 * 512, xn, mask, out);
}

// Round 8
// 210.364 us; speedup vs baseline: 3.0829x; 3.0829x over previous
//
#include <hip/hip_runtime.h>
#include <hip/hip_bf16.h>
#include <math.h>

#define B_ 4
#define S_ 2048
#define H_ 512
#define HEADS_ 8
#define DK_ 64
#define NROWS_ (B_*S_)          // 8192
#define LN_EPS_ 1e-5f
#define NEG_INF_ -1e30f
// Q pre-scale: 1/sqrt(DK) * log2(e)  (softmax done in exp2 domain)
#define QSCALE_ (0.125f * 1.44269504088896f)

typedef short s8v __attribute__((ext_vector_type(8)));   // 8 bf16 (4 VGPRs)
typedef short s4v __attribute__((ext_vector_type(4)));   // 4 bf16 (2 VGPRs)
typedef float f4v __attribute__((ext_vector_type(4)));

__device__ __forceinline__ unsigned short f2bf(float f) {
    unsigned int u = __float_as_uint(f);
    u += 0x7FFFu + ((u >> 16) & 1u);     // round-to-nearest-even
    return (unsigned short)(u >> 16);
}

__device__ __forceinline__ s4v pk4bf(float a, float b, float c, float d) {
    union { __hip_bfloat162 h[2]; s4v v; } u;
    u.h[0] = __float22bfloat162_rn(float2{a, b});
    u.h[1] = __float22bfloat162_rn(float2{c, d});
    return u.v;
}

// ---------------------------------------------------------------------------
// Kernel 0: weight transpose -> Wt (2048 x 512 bf16).
//   rows 0..511: Wq (scaled QSCALE_) | 512..1023: Wk | 1024..1535: Wv | 1536..: Wo
// ---------------------------------------------------------------------------
__global__ __launch_bounds__(256) void wt_kernel(
        const float* __restrict__ Wq, const float* __restrict__ Wk,
        const float* __restrict__ Wv, const float* __restrict__ Wo,
        unsigned short* __restrict__ Wt) {
    __shared__ float tile[32][33];
    int z = blockIdx.z;
    int k0 = blockIdx.y * 32, c0 = blockIdx.x * 32;
    const float* src;
    int ld, drow;
    float scale = 1.f;
    if (z < 24) {
        if (blockIdx.x >= 2) return;
        int zw = z >> 3, head = z & 7;
        const float* W = (zw == 0) ? Wq : (zw == 1) ? Wk : Wv;
        if (zw == 0) scale = QSCALE_;
        src = W + (size_t)head * H_ * DK_;
        ld = DK_;
        drow = zw * 512 + head * 64;
    } else {
        src = Wo; ld = H_; drow = 1536;
    }
    int tx = threadIdx.x & 31, ty = threadIdx.x >> 5;
    #pragma unroll
    for (int i = 0; i < 4; i++)
        tile[ty * 4 + i][tx] = src[(size_t)(k0 + ty * 4 + i) * ld + c0 + tx];
    __syncthreads();
    #pragma unroll
    for (int i = 0; i < 4; i++) {
        int cc = ty * 4 + i;
        Wt[(size_t)(drow + c0 + cc) * 512 + k0 + tx] = f2bf(tile[tx][cc] * scale);
    }
}

// ---------------------------------------------------------------------------
// Kernel 1: LayerNorm, wave-per-row, float4 loads. grid NROWS/4, block 256.
// ---------------------------------------------------------------------------
__global__ __launch_bounds__(256) void ln_kernel(
        const float* __restrict__ x, const float* __restrict__ gamma,
        const float* __restrict__ beta, float* __restrict__ xn,
        unsigned short* __restrict__ xnb) {
    int row  = blockIdx.x * 4 + (threadIdx.x >> 6);
    int lane = threadIdx.x & 63;
    const float4* xr = (const float4*)(x + (size_t)row * H_ + lane * 8);
    float4 a = xr[0], d = xr[1];
    float s  = (a.x + a.y) + (a.z + a.w) + (d.x + d.y) + (d.z + d.w);
    float ss = (a.x*a.x + a.y*a.y) + (a.z*a.z + a.w*a.w)
             + (d.x*d.x + d.y*d.y) + (d.z*d.z + d.w*d.w);
    #pragma unroll
    for (int i = 1; i < 64; i <<= 1) {
        s  += __shfl_xor(s, i, 64);
        ss += __shfl_xor(ss, i, 64);
    }
    float mu  = s * (1.f / 512.f);
    float var = ss * (1.f / 512.f) - mu * mu;
    float rstd = rsqrtf(var + LN_EPS_);
    const float4* gp = (const float4*)(gamma + lane * 8);
    const float4* bp = (const float4*)(beta + lane * 8);
    float4 g0 = gp[0], g1 = gp[1], b0 = bp[0], b1 = bp[1];
    float4 y0, y1;
    y0.x = (a.x - mu) * rstd * g0.x + b0.x;
    y0.y = (a.y - mu) * rstd * g0.y + b0.y;
    y0.z = (a.z - mu) * rstd * g0.z + b0.z;
    y0.w = (a.w - mu) * rstd * g0.w + b0.w;
    y1.x = (d.x - mu) * rstd * g1.x + b1.x;
    y1.y = (d.y - mu) * rstd * g1.y + b1.y;
    y1.z = (d.z - mu) * rstd * g1.z + b1.z;
    y1.w = (d.w - mu) * rstd * g1.w + b1.w;
    float4* xo = (float4*)(xn + (size_t)row * H_ + lane * 8);
    xo[0] = y0; xo[1] = y1;
    union { s4v h[2]; s8v v; } pk;
    pk.h[0] = pk4bf(y0.x, y0.y, y0.z, y0.w);
    pk.h[1] = pk4bf(y1.x, y1.y, y1.z, y1.w);
    *(s8v*)(xnb + (size_t)row * H_ + lane * 8) = pk.v;
}

// ---------------------------------------------------------------------------
// Shared MFMA GEMM tile loop (symmetric in A/B; unchanged).
// ---------------------------------------------------------------------------
#define BK_ 32
__device__ __forceinline__ void gemm_tile(
        const unsigned short* __restrict__ A,
        const unsigned short* __restrict__ Bt,
        int r0, int j0, f4v acc[4][4]) {
    __shared__ unsigned short As[128][BK_ + 8];
    __shared__ unsigned short Bs[128][BK_ + 8];
    int t = threadIdx.x;
    int wv = t >> 6, L = t & 63, c = L & 15, g = L >> 4;
    int m_base = (wv & 1) * 64, n_base = (wv >> 1) * 64;
    #pragma unroll
    for (int i = 0; i < 4; i++)
        #pragma unroll
        for (int j = 0; j < 4; j++) acc[i][j] = (f4v){0.f, 0.f, 0.f, 0.f};
    for (int k0 = 0; k0 < 512; k0 += BK_) {
        __syncthreads();
        #pragma unroll
        for (int i = 0; i < 2; i++) {
            int idx = t + i * 256;
            int m = idx >> 2, k8 = idx & 3;
            s8v va = *(const s8v*)(A  + (size_t)(r0 + m) * 512 + k0 + k8 * 8);
            s8v vb = *(const s8v*)(Bt + (size_t)(j0 + m) * 512 + k0 + k8 * 8);
            *(s8v*)(&As[m][k8 * 8]) = va;
            *(s8v*)(&Bs[m][k8 * 8]) = vb;
        }
        __syncthreads();
        s8v a[4], b[4];
        #pragma unroll
        for (int i = 0; i < 4; i++)
            a[i] = *(const s8v*)(&As[m_base + i * 16 + c][g * 8]);
        #pragma unroll
        for (int j = 0; j < 4; j++)
            b[j] = *(const s8v*)(&Bs[n_base + j * 16 + c][g * 8]);
        #pragma unroll
        for (int i = 0; i < 4; i++)
            #pragma unroll
            for (int j = 0; j < 4; j++)
                acc[i][j] = __builtin_amdgcn_mfma_f32_16x16x32_bf16(
                    a[i], b[j], acc[i][j], 0, 0, 0);
    }
}

// ---------------------------------------------------------------------------
// Kernel 2: QKV GEMM (unchanged).
// ---------------------------------------------------------------------------
__global__ __launch_bounds__(256) void qkv_gemm(
        const unsigned short* __restrict__ xnb,
        const unsigned short* __restrict__ Wt,
        unsigned short* __restrict__ Qb, unsigned short* __restrict__ Kf,
        unsigned short* __restrict__ Vf) {
    f4v acc[4][4];
    int t = threadIdx.x;
    int wv = t >> 6, L = t & 63, c = L & 15, g = L >> 4;
    int rb = wv & 1, cb = wv >> 1;
    if (blockIdx.x < 8) {
        int m0 = blockIdx.x * 128, n0 = blockIdx.y * 128;
        gemm_tile(Wt, xnb, m0, n0, acc);
        int R0 = m0 + rb * 64;            // Wt-row base (64-aligned, one head)
        int C0 = n0 + cb * 64;            // token base (64-aligned)
        int hd = (R0 >> 6) & 7;
        int b  = C0 >> 11, srow0 = C0 & 2047;
        size_t bhbase = (size_t)(b * HEADS_ + hd) * S_ * DK_;
        if (R0 < 512) {                   // ---- Q: row-major (token, dk)
            #pragma unroll
            for (int msub = 0; msub < 4; msub++) {
                int dk4 = msub * 16 + g * 4;
                #pragma unroll
                for (int nsub = 0; nsub < 4; nsub++) {
                    int tok = srow0 + nsub * 16 + c;
                    s4v v = pk4bf(acc[msub][nsub][0], acc[msub][nsub][1],
                                  acc[msub][nsub][2], acc[msub][nsub][3]);
                    *(s4v*)(Qb + bhbase + (size_t)tok * DK_ + dk4) = v;
                }
            }
        } else {                          // ---- K: fragment-major
            unsigned short* dst = Kf + bhbase + (size_t)(srow0 >> 6) * 4096;
            #pragma unroll
            for (int msub = 0; msub < 4; msub++) {
                int gx = (msub & 1) * 2 + (g >> 1);
                int slotbase = (g & 1) * 4 + (msub >> 1) * 8;
                #pragma unroll
                for (int nsub = 0; nsub < 4; nsub++) {
                    s4v v = pk4bf(acc[msub][nsub][0], acc[msub][nsub][1],
                                  acc[msub][nsub][2], acc[msub][nsub][3]);
                    *(s4v*)(dst + nsub * 1024 + (gx * 16 + c) * 16 + slotbase) = v;
                }
            }
        }
    } else {
        int r0 = blockIdx.y * 128, j0 = 1024 + (blockIdx.x - 8) * 128;
        gemm_tile(xnb, Wt, r0, j0, acc);
        int R0 = r0 + rb * 64;            // token base
        int C0 = j0 + cb * 64;            // col base
        int hd = (C0 >> 6) & 7;
        int b = R0 >> 11, srow0 = R0 & 2047;
        unsigned short* dst = Vf + (size_t)(b * HEADS_ + hd) * S_ * DK_
                              + (size_t)(srow0 >> 6) * 4096;
        #pragma unroll
        for (int msub = 0; msub < 4; msub++)
            #pragma unroll
            for (int nsub = 0; nsub < 4; nsub++) {
                s4v v = pk4bf(acc[msub][nsub][0], acc[msub][nsub][1],
                              acc[msub][nsub][2], acc[msub][nsub][3]);
                *(s4v*)(dst + nsub * 1024 + (g * 16 + c) * 16 + msub * 4) = v;
            }
    }
}

// ---------------------------------------------------------------------------
// Kernel 3: flash attention, key-split within block for occupancy.
// Block = 512 threads = 8 waves: wave wv = qsub (wv&3) x keypart (wv>>2).
// launch_bounds (512, 3): round-7's (512,8) capped the unified VGPR+AGPR
// file at 64/thread -> scratch spills (1.4 GB writes). 3 waves/EU budget
// lets the allocator land at ~72 total; HW then schedules ~6-7 waves/SIMD.
// ---------------------------------------------------------------------------
__global__ __launch_bounds__(512, 3) void attn_kernel(
        const unsigned short* __restrict__ Qb,
        const unsigned short* __restrict__ Kf,
        const unsigned short* __restrict__ Vf,
        const int* __restrict__ mask,
        unsigned short* __restrict__ hb) {
    __shared__ float red[4][64][17];     // [qsub][lane][16 acc + l]

    int wv   = threadIdx.x >> 6;
    int qsub = wv & 3;
    int kp   = wv >> 2;                  // keypart: 0 or 1
    int L  = threadIdx.x & 63;
    int c  = L & 15;            // q within wave-tile
    int g  = L >> 4;            // quad
    int bh = blockIdx.y;
    int b  = bh >> 3, n = bh & 7;
    int q0 = blockIdx.x * 64 + qsub * 16;

    const unsigned short* Qbase = Qb + (size_t)bh * S_ * DK_;
    const unsigned short* Kp = Kf + (size_t)bh * S_ * DK_ + (size_t)kp * 16 * 4096 + L * 16;
    const unsigned short* Vp = Vf + (size_t)bh * S_ * DK_ + (size_t)kp * 16 * 4096 + L * 16;
    const int* mrow = mask + b * S_ + kp * 1024;

    s8v qf0 = *(const s8v*)(Qbase + (size_t)(q0 + c) * DK_ + g * 8);
    s8v qf1 = *(const s8v*)(Qbase + (size_t)(q0 + c) * DK_ + 32 + g * 8);

    f4v acc[4];                 // O^T: d = dsub*16 + g*4 + r, q = q0 + c
    #pragma unroll
    for (int i = 0; i < 4; i++) acc[i] = (f4v){0.f, 0.f, 0.f, 0.f};
    float lac[4] = {0.f, 0.f, 0.f, 0.f};

    // prefetch K + mask for kb = 0
    s8v ka[4], kb2[4];
    int4 mk[4];
    #pragma unroll
    for (int ks = 0; ks < 4; ks++) {
        ka[ks]  = *(const s8v*)(Kp + ks * 1024);
        kb2[ks] = *(const s8v*)(Kp + ks * 1024 + 8);
        mk[ks]  = *(const int4*)(mrow + ks * 16 + g * 4);
    }

    for (int kb = 0; kb < 16; kb++) {
        // ---- V loads for current block (consumed after softmax) ----
        const unsigned short* Vn = Vp + (size_t)kb * 4096;
        s8v va[4], vb[4];
        #pragma unroll
        for (int ds = 0; ds < 4; ds++) {
            va[ds] = *(const s8v*)(Vn + ds * 1024);
            vb[ds] = *(const s8v*)(Vn + ds * 1024 + 8);
        }
        // ---- S^T MFMAs (keys on regs g*4+r, q on lanes c) ----
        f4v s[4];
        #pragma unroll
        for (int ks = 0; ks < 4; ks++) {
            f4v sv = (f4v){0.f, 0.f, 0.f, 0.f};
            sv = __builtin_amdgcn_mfma_f32_16x16x32_bf16(ka[ks],  qf0, sv, 0, 0, 0);
            sv = __builtin_amdgcn_mfma_f32_16x16x32_bf16(kb2[ks], qf1, sv, 0, 0, 0);
            s[ks] = sv;
        }
        // ---- K + mask prefetch for next block ----
        int4 mcur[4];
        #pragma unroll
        for (int ks = 0; ks < 4; ks++) mcur[ks] = mk[ks];
        if (kb < 15) {
            const unsigned short* Kn = Kp + (size_t)(kb + 1) * 4096;
            #pragma unroll
            for (int ks = 0; ks < 4; ks++) {
                ka[ks]  = *(const s8v*)(Kn + ks * 1024);
                kb2[ks] = *(const s8v*)(Kn + ks * 1024 + 8);
                mk[ks]  = *(const int4*)(mrow + (kb + 1) * 64 + ks * 16 + g * 4);
            }
        }
        // ---- mask + exp2 + partial sums (no max, no rescale) ----
        float p[4][4];
        #pragma unroll
        for (int ks = 0; ks < 4; ks++) {
            p[ks][0] = __builtin_amdgcn_exp2f(mcur[ks].x ? s[ks][0] : NEG_INF_);
            p[ks][1] = __builtin_amdgcn_exp2f(mcur[ks].y ? s[ks][1] : NEG_INF_);
            p[ks][2] = __builtin_amdgcn_exp2f(mcur[ks].z ? s[ks][2] : NEG_INF_);
            p[ks][3] = __builtin_amdgcn_exp2f(mcur[ks].w ? s[ks][3] : NEG_INF_);
            #pragma unroll
            for (int r = 0; r < 4; r++) lac[r] += p[ks][r];
        }
        // ---- P fragments (regs already B-frag of 16x16x16) ----
        s4v pf[4];
        #pragma unroll
        for (int ks = 0; ks < 4; ks++)
            pf[ks] = pk4bf(p[ks][0], p[ks][1], p[ks][2], p[ks][3]);
        // ---- O^T += V^T . P^T ----
        #pragma unroll
        for (int dsub = 0; dsub < 4; dsub++) {
            s4v v0 = __builtin_shufflevector(va[dsub], va[dsub], 0, 1, 2, 3);
            s4v v1 = __builtin_shufflevector(va[dsub], va[dsub], 4, 5, 6, 7);
            s4v v2 = __builtin_shufflevector(vb[dsub], vb[dsub], 0, 1, 2, 3);
            s4v v3 = __builtin_shufflevector(vb[dsub], vb[dsub], 4, 5, 6, 7);
            acc[dsub] = __builtin_amdgcn_mfma_f32_16x16x16bf16_1k(v0, pf[0], acc[dsub], 0, 0, 0);
            acc[dsub] = __builtin_amdgcn_mfma_f32_16x16x16bf16_1k(v1, pf[1], acc[dsub], 0, 0, 0);
            acc[dsub] = __builtin_amdgcn_mfma_f32_16x16x16bf16_1k(v2, pf[2], acc[dsub], 0, 0, 0);
            acc[dsub] = __builtin_amdgcn_mfma_f32_16x16x16bf16_1k(v3, pf[3], acc[dsub], 0, 0, 0);
        }
    }

    float l = (lac[0] + lac[1]) + (lac[2] + lac[3]);
    l += __shfl_xor(l, 16, 64);
    l += __shfl_xor(l, 32, 64);

    // ---- combine keyparts through LDS ----
    if (kp == 1) {
        float* dst = &red[qsub][L][0];
        #pragma unroll
        for (int d = 0; d < 4; d++) {
            dst[d * 4 + 0] = acc[d][0]; dst[d * 4 + 1] = acc[d][1];
            dst[d * 4 + 2] = acc[d][2]; dst[d * 4 + 3] = acc[d][3];
        }
        dst[16] = l;
    }
    __syncthreads();
    if (kp == 0) {
        const float* src = &red[qsub][L][0];
        float inv = 1.f / (l + src[16]);
        unsigned short* hp = hb + (size_t)(b * S_ + q0 + c) * H_ + n * DK_ + g * 4;
        #pragma unroll
        for (int dsub = 0; dsub < 4; dsub++) {
            s4v o4 = pk4bf((acc[dsub][0] + src[dsub * 4 + 0]) * inv,
                           (acc[dsub][1] + src[dsub * 4 + 1]) * inv,
                           (acc[dsub][2] + src[dsub * 4 + 2]) * inv,
                           (acc[dsub][3] + src[dsub * 4 + 3]) * inv);
            *(s4v*)(hp + dsub * 16) = o4;
        }
    }
}

// ---------------------------------------------------------------------------
// Kernel 4: out = (hb @ Wot^T + xn) * mask. grid (4, 64).
// ---------------------------------------------------------------------------
__global__ __launch_bounds__(256) void out_gemm(
        const unsigned short* __restrict__ hb,
        const unsigned short* __restrict__ Wot,
        const float* __restrict__ xn, const int* __restrict__ mask,
        float* __restrict__ out) {
    f4v acc[4][4];
    int r0 = blockIdx.y * 128, j0 = blockIdx.x * 128;
    gemm_tile(hb, Wot, r0, j0, acc);
    int t = threadIdx.x;
    int wv = t >> 6, L = t & 63, c = L & 15, g = L >> 4;
    int mrow = r0 + (wv & 1) * 64 + g * 4;
    int ncol = j0 + (wv >> 1) * 64 + c;
    #pragma unroll
    for (int msub = 0; msub < 4; msub++) {
        #pragma unroll
        for (int rr = 0; rr < 4; rr++) {
            int row = mrow + msub * 16 + rr;
            float mf = (float)mask[row];
            #pragma unroll
            for (int nsub = 0; nsub < 4; nsub++) {
                int col = ncol + nsub * 16;
                size_t o = (size_t)row * H_ + col;
                out[o] = (acc[msub][nsub][rr] + xn[o]) * mf;
            }
        }
    }
}

// ---------------------------------------------------------------------------
extern "C" void kernel_launch(void* const* d_in, const int* in_sizes, int n_in,
                              void* d_out, int out_size, void* d_ws, size_t ws_size,
                              hipStream_t stream) {
    const float* x     = (const float*)d_in[0];
    const int*   mask  = (const int*)d_in[1];
    const float* Wq    = (const float*)d_in[2];
    const float* Wk    = (const float*)d_in[3];
    const float* Wv    = (const float*)d_in[4];
    const float* Wo    = (const float*)d_in[5];
    const float* gamma = (const float*)d_in[6];
    const float* beta  = (const float*)d_in[7];
    float* out = (float*)d_out;

    size_t nelem = (size_t)NROWS_ * H_;   // 4M elements
    char* ws = (char*)d_ws;
    float*          xn  = (float*)ws;          ws += nelem * 4;   // 16 MB
    unsigned short* xnb = (unsigned short*)ws; ws += nelem * 2;   // 8 MB
    unsigned short* hb  = (unsigned short*)ws; ws += nelem * 2;   // 8 MB
    unsigned short* Qb  = (unsigned short*)ws; ws += nelem * 2;   // 8 MB
    unsigned short* Kf  = (unsigned short*)ws; ws += nelem * 2;   // 8 MB
    unsigned short* Vf  = (unsigned short*)ws; ws += nelem * 2;   // 8 MB
    unsigned short* Wt  = (unsigned short*)ws;                    // 2 MB

    wt_kernel<<<dim3(16, 16, 25), 256, 0, stream>>>(Wq, Wk, Wv, Wo, Wt);
    ln_kernel<<<NROWS_ / 4, 256, 0, stream>>>(x, gamma, beta, xn, xnb);
    qkv_gemm<<<dim3(12, 64), 256, 0, stream>>>(xnb, Wt, Qb, Kf, Vf);
    attn_kernel<<<dim3(S_ / 64, B_ * HEADS_), 512, 0, stream>>>(
        Qb, Kf, Vf, mask, hb);
    out_gemm<<<dim3(4, 64), 256, 0, stream>>>(
        hb, Wt + (size_t)1536 * 512, xn, mask, out);
}